// Round 1
// baseline (192.657 us; speedup 1.0000x reference)
//
#include <hip/hip_runtime.h>

#define F_DIM 128
#define TE_DIM 32
#define DD 160
#define NB 4096
#define KK 64
#define ROWS 4
#define LD 164  // padded LDS row stride: 164 % 32 = 4 -> conflict-free 4-row access

__device__ __forceinline__ float dot4acc(const float4 w, const float4 v, float a) {
    a = fmaf(w.x, v.x, a);
    a = fmaf(w.y, v.y, a);
    a = fmaf(w.z, v.z, a);
    a = fmaf(w.w, v.w, a);
    return a;
}

__device__ __forceinline__ float wave_max(float v) {
    #pragma unroll
    for (int off = 32; off > 0; off >>= 1) v = fmaxf(v, __shfl_xor(v, off, 64));
    return v;
}
__device__ __forceinline__ float wave_sum(float v) {
    #pragma unroll
    for (int off = 32; off > 0; off >>= 1) v += __shfl_xor(v, off, 64);
    return v;
}

// Block-cooperative GEMV: vout[r][d] = sum_f W[d][f] * vin[r][f] + bias[d]
// for r in 0..3, d in 0..159. Thread (r = tid&3, dl = tid>>2) handles
// d in {dl, dl+64, dl+128(dl<32)} for its r. Lanes 4t..4t+3 read identical
// weight addresses -> coalescer dedups -> W read once per block.
__device__ __forceinline__ void gemv_rows(
    const float* __restrict__ W, const float* __restrict__ bias,
    const float (*vin)[LD], float (*vout)[LD], int tid)
{
    const int r  = tid & 3;
    const int dl = tid >> 2;  // 0..63, wave-uniform dl<32 split
    const float4* v4 = (const float4*)vin[r];
    const float4* w0 = (const float4*)(W + (long)dl * DD);
    const float4* w1 = (const float4*)(W + (long)(dl + 64) * DD);
    float a0 = bias[dl];
    float a1 = bias[dl + 64];
    if (dl < 32) {
        const float4* w2 = (const float4*)(W + (long)(dl + 128) * DD);
        float a2 = bias[dl + 128];
        #pragma unroll 8
        for (int f = 0; f < 40; ++f) {
            const float4 v = v4[f];
            a0 = dot4acc(w0[f], v, a0);
            a1 = dot4acc(w1[f], v, a1);
            a2 = dot4acc(w2[f], v, a2);
        }
        vout[r][dl]       = a0;
        vout[r][dl + 64]  = a1;
        vout[r][dl + 128] = a2;
    } else {
        #pragma unroll 8
        for (int f = 0; f < 40; ++f) {
            const float4 v = v4[f];
            a0 = dot4acc(w0[f], v, a0);
            a1 = dot4acc(w1[f], v, a1);
        }
        vout[r][dl]      = a0;
        vout[r][dl + 64] = a1;
    }
}

__global__ __launch_bounds__(256, 4)
void structure_learner_kernel(
    const float* __restrict__ x,
    const int*   __restrict__ target_node_ids,
    const int*   __restrict__ target_node_times,
    const int*   __restrict__ neighbor_ids,
    const int*   __restrict__ edge_time,
    const float* __restrict__ edge_weight,
    const float* __restrict__ gumbel_u,
    const float* __restrict__ te_w,
    const float* __restrict__ te_b,
    const float* __restrict__ in_proj_w,
    const float* __restrict__ in_proj_b,
    const float* __restrict__ out_w,
    const float* __restrict__ out_b,
    const float* __restrict__ mlp_w,
    const float* __restrict__ mlp_b,
    float* __restrict__ out_ao,
    float* __restrict__ out_new,
    float* __restrict__ out_mask)
{
    __shared__ __attribute__((aligned(16))) float s_qin[ROWS][LD];
    __shared__ __attribute__((aligned(16))) float s_q[ROWS][LD];
    __shared__ __attribute__((aligned(16))) float s_qt[ROWS][LD];
    __shared__ __attribute__((aligned(16))) float s_wkv[ROWS][LD];
    __shared__ __attribute__((aligned(16))) float s_ctx[ROWS][LD];
    __shared__ __attribute__((aligned(16))) float s_ao[ROWS][LD];
    __shared__ float s_attnw[ROWS][KK];
    __shared__ float s_sbk[ROWS];
    __shared__ int   s_nid[ROWS][KK];
    __shared__ float s_et[ROWS][KK];

    const int tid  = threadIdx.x;
    const int wr   = tid >> 6;   // wave id == row for per-row phases
    const int lane = tid & 63;
    const int b0   = blockIdx.x * ROWS;

    // ---------------- P0: load neighbor meta + build q_in ----------------
    {
        const int b = b0 + wr;
        s_nid[wr][lane] = neighbor_ids[(long)b * KK + lane];
        s_et[wr][lane]  = (float)edge_time[(long)b * KK + lane];
        const int tn = target_node_ids[b];
        const float2 tx = *(const float2*)(x + (long)tn * F_DIM + lane * 2);
        s_qin[wr][lane * 2]     = tx.x;
        s_qin[wr][lane * 2 + 1] = tx.y;
        if (lane < TE_DIM) {
            const float tt = (float)target_node_times[b];
            s_qin[wr][F_DIM + lane] = cosf(tt * te_w[lane] + te_b[lane]);
        }
    }
    __syncthreads();

    // ---------------- P1: q = Wq @ q_in + bq ----------------
    gemv_rows(in_proj_w, in_proj_b, s_qin, s_q, tid);
    __syncthreads();

    // ---------------- P2: q_tilde[e] = sum_d Wk[d][e] q[d] ; sbk = q·bk ----
    {
        if (tid < 160) {
            const int r  = tid / 40;
            const int e4 = tid % 40;  // float4 column block, coalesced
            float4 acc = make_float4(0.f, 0.f, 0.f, 0.f);
            const float* qr = s_q[r];
            #pragma unroll 8
            for (int d = 0; d < DD; ++d) {
                const float qd = qr[d];
                const float4 wv = *((const float4*)(in_proj_w + (long)(DD + d) * DD) + e4);
                acc.x = fmaf(qd, wv.x, acc.x);
                acc.y = fmaf(qd, wv.y, acc.y);
                acc.z = fmaf(qd, wv.z, acc.z);
                acc.w = fmaf(qd, wv.w, acc.w);
            }
            *((float4*)s_qt[r] + e4) = acc;
        } else if (tid < 160 + ROWS) {
            const int r = tid - 160;
            float acc = 0.f;
            for (int d = 0; d < DD; ++d)
                acc = fmaf(s_q[r][d], in_proj_b[DD + d], acc);
            s_sbk[r] = acc;
        }
    }
    __syncthreads();

    // ---------------- P3: scores + softmax (wave per row, lane = k) -------
    float my_aw;
    {
        const int r   = wr;
        const int nid = s_nid[r][lane];
        const float et = s_et[r][lane];
        const float4* xr  = (const float4*)(x + (long)nid * F_DIM);
        const float4* qt4 = (const float4*)s_qt[r];
        float acc = 0.f;
        #pragma unroll 8
        for (int f = 0; f < F_DIM / 4; ++f)
            acc = dot4acc(xr[f], qt4[f], acc);
        const float* qtte = s_qt[r] + F_DIM;
        #pragma unroll 8
        for (int j = 0; j < TE_DIM; ++j) {
            const float te = cosf(et * te_w[j] + te_b[j]);
            acc = fmaf(qtte[j], te, acc);
        }
        const float sc = (acc + s_sbk[r]) / sqrtf(160.0f);
        const float m = wave_max(sc);
        const float e = expf(sc - m);
        const float l = wave_sum(e);
        my_aw = e / l;
        s_attnw[r][lane] = my_aw;
    }
    __syncthreads();

    // ---------------- P4: wkv = sum_k attn_w[k] * kv[k] (wave per row) ----
    {
        const int r = wr;
        float ax = 0.f, ay = 0.f, at = 0.f;
        const float twl = (lane < TE_DIM) ? te_w[lane] : 0.f;
        const float tbl = (lane < TE_DIM) ? te_b[lane] : 0.f;
        const float* xb = x + lane * 2;
        #pragma unroll 4
        for (int k = 0; k < KK; ++k) {
            const float w   = s_attnw[r][k];
            const int   nid = s_nid[r][k];
            const float2 xv = *(const float2*)(xb + (long)nid * F_DIM);
            ax = fmaf(w, xv.x, ax);
            ay = fmaf(w, xv.y, ay);
            const float te = cosf(s_et[r][k] * twl + tbl);
            at = fmaf(w, te, at);
        }
        s_wkv[r][lane * 2]     = ax;
        s_wkv[r][lane * 2 + 1] = ay;
        if (lane < TE_DIM) s_wkv[r][F_DIM + lane] = at;
    }
    __syncthreads();

    // ---------------- P5: ctx = Wv @ wkv + bv -----------------------------
    gemv_rows(in_proj_w + (long)2 * DD * DD, in_proj_b + 2 * DD, s_wkv, s_ctx, tid);
    __syncthreads();

    // ---------------- P6: attn_out = out_w @ ctx + out_b ------------------
    gemv_rows(out_w, out_b, s_ctx, s_ao, tid);
    __syncthreads();

    // ---------------- P7: epilogue (wave per row, lane = k) ---------------
    {
        const int r = wr;
        const int b = b0 + r;
        // mlp base = dot(attn_out, mlp_w[0:160]) + mlp_b
        float p = s_ao[r][lane] * mlp_w[lane];
        p = fmaf(s_ao[r][lane + 64], mlp_w[lane + 64], p);
        if (lane < 32) p = fmaf(s_ao[r][lane + 128], mlp_w[lane + 128], p);
        const float base = wave_sum(p) + mlp_b[0];

        // store attn_output (coalesced)
        float* ao = out_ao + (long)b * DD;
        ao[lane]      = s_ao[r][lane];
        ao[lane + 64] = s_ao[r][lane + 64];
        if (lane < 32) ao[lane + 128] = s_ao[r][lane + 128];

        // gumbel softmax -> mask
        const float u = gumbel_u[(long)b * KK + lane];
        const float g = -logf(-logf(u + 1e-10f) + 1e-10f);
        const float z = my_aw + g;  // TAU = 1.0 (exact no-op divide)
        const float m = wave_max(z);
        const float e = expf(z - m);
        const float l = wave_sum(e);
        const float y = e / l;
        out_mask[(long)b * KK + lane] = (y > 0.2f) ? 1.0f : 0.0f;

        // new edge weight: leaky_relu(base + ew * mlp_w[160])
        const float ew  = edge_weight[(long)b * KK + lane];
        const float val = fmaf(ew, mlp_w[160], base);
        out_new[(long)b * KK + lane] = (val >= 0.f) ? val : 0.01f * val;
    }
}

extern "C" void kernel_launch(void* const* d_in, const int* in_sizes, int n_in,
                              void* d_out, int out_size, void* d_ws, size_t ws_size,
                              hipStream_t stream) {
    const float* x   = (const float*)d_in[0];
    const int*   tni = (const int*)d_in[1];
    const int*   tnt = (const int*)d_in[2];
    const int*   nid = (const int*)d_in[3];
    const int*   et  = (const int*)d_in[4];
    const float* ew  = (const float*)d_in[5];
    const float* gu  = (const float*)d_in[6];
    const float* tew = (const float*)d_in[7];
    const float* teb = (const float*)d_in[8];
    const float* ipw = (const float*)d_in[9];
    const float* ipb = (const float*)d_in[10];
    const float* ow  = (const float*)d_in[11];
    const float* ob  = (const float*)d_in[12];
    const float* mw  = (const float*)d_in[13];
    const float* mb  = (const float*)d_in[14];

    float* out      = (float*)d_out;
    float* out_ao   = out;                                  // [4096][160]
    float* out_new  = out + (long)NB * DD;                  // [4096][64]
    float* out_mask = out + (long)NB * DD + (long)NB * KK;  // [4096][64]

    dim3 grid(NB / ROWS);
    dim3 block(256);
    structure_learner_kernel<<<grid, block, 0, stream>>>(
        x, tni, tnt, nid, et, ew, gu, tew, teb, ipw, ipb, ow, ob, mw, mb,
        out_ao, out_new, out_mask);
}